// Round 22
// baseline (100.683 us; speedup 1.0000x reference)
//
#include <hip/hip_runtime.h>
#include <hip/hip_bf16.h>
#include <cstdint>

typedef __attribute__((ext_vector_type(8))) short bf16x8;
typedef __attribute__((ext_vector_type(4))) float f32x4;
typedef __attribute__((ext_vector_type(4))) unsigned int u32x4;
typedef __attribute__((ext_vector_type(2))) unsigned int u32x2;
typedef __attribute__((ext_vector_type(8))) unsigned short u16x8;
typedef __attribute__((ext_vector_type(4))) unsigned short u16x4;

#define DEV static __device__ __forceinline__

DEV unsigned short f2b(float x) {
    __hip_bfloat16 b = __float2bfloat16(x);
    return __builtin_bit_cast(unsigned short, b);
}
DEV float b2f(unsigned short u) {
    __hip_bfloat16 b = __builtin_bit_cast(__hip_bfloat16, u);
    return __bfloat162float(b);
}
// 2xf32 -> packed bf16x2 dword via HIP intrinsic (emits v_cvt_pk_bf16_f32;
// RNE, bit-identical to f2b pair). a -> low 16 bits. memcpy because
// __hip_bfloat162 is not trivially copyable (bit_cast rejected).
DEV unsigned pk2(float a, float b) {
    __hip_bfloat162 h = __float22bfloat162_rn(float2{a, b});
    unsigned r;
    __builtin_memcpy(&r, &h, 4);
    return r;
}

// raw v_exp_f32 (exp2); flushes exp2(x<-126) to 0 — right for softmax.
#if __has_builtin(__builtin_amdgcn_exp2f)
#define EXP2(x) __builtin_amdgcn_exp2f(x)
#else
#define EXP2(x) exp2f(x)
#endif

// async global->LDS, 16B per lane. LDS base wave-uniform; HW adds lane*16.
typedef __attribute__((address_space(1))) unsigned char as1_u8;
typedef __attribute__((address_space(3))) unsigned char as3_u8;
DEV void gload16(const void* g, void* l) {
    __builtin_amdgcn_global_load_lds((as1_u8*)(uintptr_t)g, (as3_u8*)(uintptr_t)l,
                                     16, 0, 0);
}

#define LOG2E 1.4426950408889634f

// ---------------------------------------------------------------------------
// merged prep: [0,1536) qkv weights | [1536,2304) proj weights | rest: x->bf16
// ---------------------------------------------------------------------------
__global__ void prep_all(const float* __restrict__ qw, const float* __restrict__ qg,
                         const float* __restrict__ qbe, const float* __restrict__ qmu,
                         const float* __restrict__ qva,
                         const float* __restrict__ pw, const float* __restrict__ pg,
                         const float* __restrict__ pbe, const float* __restrict__ pmu,
                         const float* __restrict__ pva,
                         const float* __restrict__ x,
                         unsigned short* __restrict__ wT, float* __restrict__ t1,
                         unsigned short* __restrict__ pwT, float* __restrict__ t2,
                         unsigned short* __restrict__ xb)
{
    int blk = blockIdx.x, tid = threadIdx.x;
    if (blk < 1536) {                       // qkv W: fold BN, transpose, q*SCALE*log2e
        int gid = blk * 256 + tid;
        int c = gid & 1023, k = gid >> 10;
        float s = qg[c] * rsqrtf(qva[c] + 1e-5f);
        float qs = ((c & 127) < 32) ? (0.17677669529663687f * LOG2E) : 1.0f;
        float val = qw[(size_t)k * 1024 + c] * s * qs;
        wT[(size_t)c * 384 + k] = f2b(val);
        if (k == 0) t1[c] = (qbe[c] - qmu[c] * s) * qs;
    } else if (blk < 2304) {                // proj W: hi/lo split -> [W_hi | W_lo]
        int gid = (blk - 1536) * 256 + tid;
        int c = gid % 384, k = gid / 384;
        float s = pg[c] * rsqrtf(pva[c] + 1e-5f);
        float val = pw[(size_t)k * 384 + c] * s;
        unsigned short hi = f2b(val);
        unsigned short lo = f2b(val - b2f(hi));
        size_t base = (size_t)c * 1024;
        pwT[base + k]       = hi;
        pwT[base + 512 + k] = lo;
        if (k == 0) t2[c] = pbe[c] - pmu[c] * s;
    } else {                                // x fp32 -> bf16, 8 elems/thread
        int gid = (blk - 2304) * 256 + tid;
        const f32x4* p = (const f32x4*)(x + (size_t)gid * 8);
        f32x4 a = p[0], bq = p[1];
        u16x8 o;
        #pragma unroll
        for (int t = 0; t < 4; ++t) { o[t] = f2b(a[t]); o[4 + t] = f2b(bq[t]); }
        *(u16x8*)(xb + (size_t)gid * 8) = o;
    }
}

// ---------------------------------------------------------------------------
// GEMM: C[M,N] = A[M,K] * Bt[N,K]^T (+tvec[col]).  m97 2-barrier loop, both
// tiles via global_load_lds width-16.  1D grid, XCD-swizzled.
// DUAL=1 (proj): B has layout [N][2*Kdim] = [W_hi | W_lo]; per k-tile the A
// tile is staged ONCE and BOTH B halves are staged; inner loop runs hi+lo
// MFMAs into the same acc (2x MFMA per barrier, A traffic halved).
// EPI=0: q/k scatter bf16 + V written directly transposed (vt[bh][vd][tok]).
// EPI=1: fp32 out (proj).  LB: min blocks/CU for launch_bounds.
// ---------------------------------------------------------------------------
template<int BM, int BN, int EPI, int MB, int NB, int LB, int DUAL>
__launch_bounds__(256, LB)
__global__ void gemm_bt(const unsigned short* __restrict__ Ab,
                        const unsigned short* __restrict__ Bt,
                        int Kdim, int Astride,
                        const float* __restrict__ tvec,
                        unsigned short* __restrict__ outq,
                        unsigned short* __restrict__ outk,
                        unsigned short* __restrict__ outvt,
                        float* __restrict__ outf)
{
    constexpr int BK = 64;
    constexpr int WM = BM / 2, WN = BN / 2;
    constexpr int MI = WM / 16, NI = WN / 16;
    constexpr int NCA = BM * 128 / 1024; // 1KB wave-chunks in A tile
    constexpr int NCB = BN * 128 / 1024;
    constexpr int NH = DUAL ? 2 : 1;

    __shared__ __align__(16) unsigned short As[BM * BK];
    __shared__ __align__(16) unsigned short Bs[NH * BN * BK];

    const int tid = threadIdx.x;
    const int lane = tid & 63, w = tid >> 6;
    const int l15 = lane & 15, lg = lane >> 4;
    const int wr = w >> 1, wc = w & 1;

    const int bid = blockIdx.x;
    const int xcd = bid & 7, idx = bid >> 3;
    const int m0 = (xcd * (MB / 8) + idx / NB) * BM;
    const int n0 = (idx % NB) * BN;

    const int brstride = DUAL ? 2 * Kdim : Kdim;   // B row stride (elems)

    f32x4 acc[MI][NI];
    #pragma unroll
    for (int i = 0; i < MI; ++i)
        #pragma unroll
        for (int j = 0; j < NI; ++j) acc[i][j] = (f32x4){0.f, 0.f, 0.f, 0.f};

    const int nk = Kdim / BK;

    for (int kb = 0; kb < nk; ++kb) {
        const int k0 = kb * BK;
        #pragma unroll
        for (int i = 0; i < NCA / 4; ++i) {
            int c = w + i * 4;
            int bo = c * 1024 + lane * 16;
            gload16((const char*)Ab + ((size_t)(m0 + (bo >> 7)) * Astride + k0) * 2 + (bo & 127),
                    (char*)As + c * 1024);
        }
        #pragma unroll
        for (int h2 = 0; h2 < NH; ++h2)
        #pragma unroll
        for (int i = 0; i < NCB / 4; ++i) {
            int c = w + i * 4;
            int bo = c * 1024 + lane * 16;
            gload16((const char*)Bt + ((size_t)(n0 + (bo >> 7)) * brstride + k0 + h2 * Kdim) * 2 + (bo & 127),
                    (char*)Bs + h2 * (BN * BK * 2) + c * 1024);
        }
        __syncthreads();   // drains vmcnt: tile ready

        #pragma unroll
        for (int ks = 0; ks < 2; ++ks) {
            bf16x8 af[MI], bfr[NH][NI];
            #pragma unroll
            for (int mi = 0; mi < MI; ++mi)
                af[mi] = *(const bf16x8*)(&As[(wr * WM + mi * 16 + l15) * 64 + ks * 32 + lg * 8]);
            #pragma unroll
            for (int h2 = 0; h2 < NH; ++h2)
            #pragma unroll
            for (int ni = 0; ni < NI; ++ni)
                bfr[h2][ni] = *(const bf16x8*)(&Bs[h2 * BN * BK +
                                               (wc * WN + ni * 16 + l15) * 64 + ks * 32 + lg * 8]);
            #pragma unroll
            for (int mi = 0; mi < MI; ++mi)
                #pragma unroll
                for (int ni = 0; ni < NI; ++ni) {
                    acc[mi][ni] = __builtin_amdgcn_mfma_f32_16x16x32_bf16(
                        af[mi], bfr[0][ni], acc[mi][ni], 0, 0, 0);
                    if constexpr (DUAL)
                        acc[mi][ni] = __builtin_amdgcn_mfma_f32_16x16x32_bf16(
                            af[mi], bfr[1][ni], acc[mi][ni], 0, 0, 0);
                }
        }
        if (kb + 1 < nk) __syncthreads();
    }

    #pragma unroll
    for (int mi = 0; mi < MI; ++mi)
    #pragma unroll
    for (int ni = 0; ni < NI; ++ni) {
        int col = n0 + wc * WN + ni * 16 + l15;
        int row0 = m0 + wr * WM + mi * 16 + lg * 4;
        if constexpr (EPI == 0) {
            int bb = row0 >> 10, n = row0 & 1023;
            int hh = col >> 7, t = col & 127;
            size_t bhh = (size_t)(bb * 8 + hh);
            if (t < 64) {
                #pragma unroll
                for (int j = 0; j < 4; ++j) {
                    unsigned short bv = f2b(acc[mi][ni][j] + tvec[col]);
                    size_t base = (bhh * 1024 + n + j) * 32;
                    if (t < 32) outq[base + t] = bv;
                    else        outk[base + (t - 32)] = bv;
                }
            } else {
                u16x4 pv;
                #pragma unroll
                for (int j = 0; j < 4; ++j) pv[j] = f2b(acc[mi][ni][j] + tvec[col]);
                *(u16x4*)(outvt + (bhh * 64 + (t - 64)) * 1024 + n) = pv;
            }
        } else {
            #pragma unroll
            for (int j = 0; j < 4; ++j)
                outf[(size_t)(row0 + j) * 384 + col] = acc[mi][ni][j] + tvec[col];
        }
    }
}

// ---------------------------------------------------------------------------
// fused flash attention, SWAPPED QK^T + STATIC-MAX softmax, QBLK=128 (r21)
// + REFLECTED BIAS TABLE: biasrow2[dx][t] = bias[dx][|t-31|]*log2e (32x64
// f32, 8KB LDS) makes the per-lane bias address LINEAR in j (t = yi-yj+31
// descends by 1 as j ascends), so each (dx,p) group's 4 reads are 4
// contiguous floats consumed reverse-indexed (compile-time permutation) —
// the compiler merges them into ds_read2_b32 pairs, halving the bias LDS
// issue (the largest term of the r17/r21 LDS audit: 186 of 418 cyc).
// Each wave owns 32 q-rows (2 Q-frags u=0,1); same-iteration PV; in-loop
// bias; P stored immediately per u; __launch_bounds__(256,3) — no spill.
// V^T 2-buffered via global_load_lds: stage(kb+1) after the region-kb
// barrier into cur^1 while PV(kb) reads cur; counted s_waitcnt vmcnt(4)
// retires the 2 stage ops while this iter's 4 K loads stay in flight;
// vmcnt(0) only on the last iteration.  P = exp2(s) unnormalized
// (accS<=2^24; O=acc/accS scale-invariant).
// 1D grid, bid = qb*128 + bh pins each bh's 8 blocks to one XCD (K/V L2).
// epilogue: /accS, hardswish, single bf16 store -> O[tok][512]
// ---------------------------------------------------------------------------
__launch_bounds__(256, 3)
__global__ void attn_kernel(const unsigned short* __restrict__ q,
                            const unsigned short* __restrict__ kmat,
                            const unsigned short* __restrict__ vt,
                            const float* __restrict__ ab,
                            unsigned short* __restrict__ O)
{
    __shared__ __align__(16) unsigned short Vls[2][64 * 64];  // swizzled [vd][key]
    __shared__ __align__(16) unsigned short Pls[4 * 32 * 64]; // per-wave [q][k]
    __shared__ float biasrow2[32 * 64];   // reflected: [dx][yi-yj+31]

    const int tid = threadIdx.x;
    const int lane = tid & 63, w = tid >> 6;
    const int l15 = lane & 15, lg = lane >> 4;
    const int bid = blockIdx.x;
    const int qb = bid >> 7, bh = bid & 127;
    const int h = bh & 7, b = bh >> 3;

    // reflected bias table init: biasrow2[dx*64+t] = ab[h][dx*32+|t-31|]*log2e
    for (int i = tid; i < 2048; i += 256) {
        int dx = i >> 6, t = i & 63;
        int d = t - 31; d = d < 0 ? -d : d;
        biasrow2[i] = (t < 63) ? ab[h * 1024 + dx * 32 + d] * LOG2E : 0.f;
    }

    // two Q B-frags per wave (col=q=lane&15, k=d); rows 16 apart share xi
    const int qrow0 = qb * 128 + w * 32 + l15;
    bf16x8 aq[2];
    aq[0] = *(const bf16x8*)(q + ((size_t)bh * 1024 + qrow0) * 32 + lg * 8);
    aq[1] = *(const bf16x8*)(q + ((size_t)bh * 1024 + qrow0 + 16) * 32 + lg * 8);

    const int xi = qrow0 >> 5;            // same for both u (qrow0&31 = l15 < 16)
    // per (u,p) byte offset of the j=3 element: t3 = yi - p*16 - lg*4 + 28
    int tyoff[2][2];
    #pragma unroll
    for (int u = 0; u < 2; ++u) {
        int yi = l15 + u * 16;
        #pragma unroll
        for (int p = 0; p < 2; ++p)
            tyoff[u][p] = (yi - p * 16 - lg * 4 + 28) * 4;
    }

    f32x4 acc[2][4], accS[2];
    #pragma unroll
    for (int u = 0; u < 2; ++u) {
        #pragma unroll
        for (int cf = 0; cf < 4; ++cf) acc[u][cf] = (f32x4){0.f, 0.f, 0.f, 0.f};
        accS[u] = (f32x4){0.f, 0.f, 0.f, 0.f};
    }

    const short oneb = (short)0x3F80;
    const bf16x8 onesb = {oneb, oneb, oneb, oneb, oneb, oneb, oneb, oneb};

    const unsigned short* kbase = kmat + (size_t)bh * 1024 * 32 + lg * 8;

    // V gload_lds geometry: lane feeds rows vrow / vrow+32 with pre-swizzled
    // source key chunk so the XOR LDS layout materializes.
    const int vrow = w * 8 + (lane >> 3);
    const int vkel = ((lane & 7) ^ (lane >> 3)) * 8;
    const unsigned short* vsrc0 = vt + ((size_t)bh * 64 + vrow) * 1024 + vkel;
    const unsigned short* vsrc1 = vsrc0 + (size_t)32 * 1024;

    // P bases: wave block 4KB; row u*16+l15; swizzle (l15&7)<<4 (row&7=l15&7)
    char* const pw_base = (char*)Pls + w * 4096 + l15 * 128;
    const int pswz = (l15 & 7) << 4;

    // prolog: stage V tile 0 (async), prefetch K frags for tile 0
    gload16(vsrc0, (char*)Vls[0] + w * 1024);
    gload16(vsrc1, (char*)Vls[0] + w * 1024 + 4096);
    bf16x8 kf[4];
    #pragma unroll
    for (int cf = 0; cf < 4; ++cf)
        kf[cf] = *(const bf16x8*)(kbase + (size_t)(cf * 16 + l15) * 32);
    __syncthreads();   // full drain once: covers biasrow2 + Vls[0]

    int cur = 0;
    for (int kb = 0; kb < 16; ++kb) {
        // bias x-distance (shared by both u; row stride 64 floats = 256B)
        int dx0 = xi - 2 * kb;     dx0 = (dx0 < 0 ? -dx0 : dx0) * 256;
        int dx1 = xi - 2 * kb - 1; dx1 = (dx1 < 0 ? -dx1 : dx1) * 256;

        // per u: bias C-in (4 contiguous LDS floats per (dx,p), reversed),
        // QK(kb), exp/pack, store P(u).  s[] transient per u.
        #pragma unroll
        for (int u = 0; u < 2; ++u) {
            f32x4 s[4];
            __builtin_amdgcn_s_setprio(1);
            #pragma unroll
            for (int cf = 0; cf < 4; ++cf) {
                const int dxo = (cf >> 1) ? dx1 : dx0;
                const float* bp = (const float*)((const char*)biasrow2 +
                                                 (dxo + tyoff[u][cf & 1]));
                f32x4 c = {bp[3], bp[2], bp[1], bp[0]};   // reversed: c[j]=bias(j)
                s[cf] = __builtin_amdgcn_mfma_f32_16x16x32_bf16(
                    kf[cf], aq[u], c, 0, 0, 0);
            }
            __builtin_amdgcn_s_setprio(0);
            char* pwu = pw_base + u * 2048;
            #pragma unroll
            for (int cf = 0; cf < 4; ++cf) {
                unsigned lo = pk2(EXP2(s[cf][0]), EXP2(s[cf][1]));
                unsigned hi = pk2(EXP2(s[cf][2]), EXP2(s[cf][3]));
                *(u32x2*)(pwu + ((cf * 32 + lg * 8) ^ pswz)) = (u32x2){lo, hi};
            }
        }

        // K frags for kb+1 (after both QKs consumed the old ones)
        if (kb < 15) {
            #pragma unroll
            for (int cf = 0; cf < 4; ++cf)
                kf[cf] = *(const bf16x8*)(kbase + (size_t)((kb + 1) * 64 + cf * 16 + l15) * 32);
        }

        // counted-vmcnt barrier: newer ops = 4 K loads; waiting to 4 retires
        // the 2 older V-stage gloads (in-order). Last iter: full drain.
        if (kb < 15) {
            __asm__ volatile("s_waitcnt vmcnt(4)" ::: "memory");
        } else {
            __asm__ volatile("s_waitcnt vmcnt(0)" ::: "memory");
        }
        __builtin_amdgcn_s_barrier();

        // region kb: stage V(kb+1) into cur^1 while PV(kb) reads cur
        if (kb < 15) {
            gload16(vsrc0 + (kb + 1) * 64, (char*)Vls[cur ^ 1] + w * 1024);
            gload16(vsrc1 + (kb + 1) * 64, (char*)Vls[cur ^ 1] + w * 1024 + 4096);
        }

        // PV(kb): each V^T frag read once, used by both u-blocks (20 MFMAs)
        __builtin_amdgcn_s_setprio(1);
        #pragma unroll
        for (int ks = 0; ks < 2; ++ks) {
            const bf16x8 pa0 = *(const bf16x8*)(pw_base + ((ks * 64 + lg * 16) ^ pswz));
            const bf16x8 pa1 = *(const bf16x8*)(pw_base + 2048 + ((ks * 64 + lg * 16) ^ pswz));
            accS[0] = __builtin_amdgcn_mfma_f32_16x16x32_bf16(pa0, onesb, accS[0], 0, 0, 0);
            accS[1] = __builtin_amdgcn_mfma_f32_16x16x32_bf16(pa1, onesb, accS[1], 0, 0, 0);
            #pragma unroll
            for (int cf = 0; cf < 4; ++cf) {
                const bf16x8 vb = *(const bf16x8*)((char*)Vls[cur] + (cf * 16 + l15) * 128 +
                                                   ((ks * 64 + lg * 16) ^ (((cf * 16 + l15) & 7) << 4)));
                acc[0][cf] = __builtin_amdgcn_mfma_f32_16x16x32_bf16(pa0, vb, acc[0][cf], 0, 0, 0);
                acc[1][cf] = __builtin_amdgcn_mfma_f32_16x16x32_bf16(pa1, vb, acc[1][cf], 0, 0, 0);
            }
        }
        __builtin_amdgcn_s_setprio(0);

        cur ^= 1;
    }

    // epilogue: normalize, hardswish, single bf16 store per u-block
    #pragma unroll
    for (int u = 0; u < 2; ++u) {
        float rinv[4];
        #pragma unroll
        for (int j = 0; j < 4; ++j) rinv[j] = 1.f / accS[u][j];
        #pragma unroll
        for (int cf = 0; cf < 4; ++cf)
        #pragma unroll
        for (int j = 0; j < 4; ++j) {
            float ov = acc[u][cf][j] * rinv[j];
            float hs = ov * fminf(fmaxf(ov + 3.f, 0.f), 6.f) * (1.f / 6.f);
            size_t tok = (size_t)b * 1024 + qb * 128 + w * 32 + u * 16 + lg * 4 + j;
            O[tok * 512 + h * 64 + cf * 16 + l15] = f2b(hs);
        }
    }
}

// ---------------------------------------------------------------------------
extern "C" void kernel_launch(void* const* d_in, const int* in_sizes, int n_in,
                              void* d_out, int out_size, void* d_ws, size_t ws_size,
                              hipStream_t stream)
{
    const float* x   = (const float*)d_in[0];
    const float* qw  = (const float*)d_in[1];
    const float* qg  = (const float*)d_in[2];
    const float* qbe = (const float*)d_in[3];
    const float* qmu = (const float*)d_in[4];
    const float* qva = (const float*)d_in[5];
    const float* pw  = (const float*)d_in[6];
    const float* pg  = (const float*)d_in[7];
    const float* pbe = (const float*)d_in[8];
    const float* pmu = (const float*)d_in[9];
    const float* pva = (const float*)d_in[10];
    const float* ab  = (const float*)d_in[11];

    char* ws = (char*)d_ws;
    size_t off = 0;
    auto alloc = [&](size_t bytes) {
        size_t o = off; off = (off + bytes + 255) & ~(size_t)255; return o;
    };

    size_t o_o   = alloc((size_t)16384 * 512 * 2);   // O bf16 (plain)
    size_t o_wT  = alloc((size_t)1024 * 384 * 2);
    size_t o_pwT = alloc((size_t)384 * 1024 * 2);    // [W_hi | W_lo]
    size_t o_t1  = alloc(1024 * 4);
    size_t o_t2  = alloc(384 * 4);
    size_t o_q   = alloc((size_t)16 * 8 * 1024 * 32 * 2);
    size_t o_k   = alloc((size_t)16 * 8 * 1024 * 32 * 2);
    size_t o_vt  = alloc((size_t)16 * 8 * 1024 * 64 * 2);
    size_t o_xb  = alloc((size_t)16384 * 384 * 2);

    unsigned short* Obuf = (unsigned short*)(ws + o_o);
    unsigned short* wT   = (unsigned short*)(ws + o_wT);
    unsigned short* pwT  = (unsigned short*)(ws + o_pwT);
    float* t1 = (float*)(ws + o_t1);
    float* t2 = (float*)(ws + o_t2);
    unsigned short* qb_ = (unsigned short*)(ws + o_q);
    unsigned short* kb_ = (unsigned short*)(ws + o_k);
    unsigned short* vtb = (unsigned short*)(ws + o_vt);
    unsigned short* xb  = (unsigned short*)(ws + o_xb);

    prep_all<<<5376, 256, 0, stream>>>(qw, qg, qbe, qmu, qva,
                                       pw, pg, pbe, pmu, pva,
                                       x, wT, t1, pwT, t2, xb);

    // qkv GEMM: both tiles via global_load_lds; 1024 blocks = exactly 4/CU
    gemm_bt<128, 128, 0, 128, 8, 4, 0><<<1024, 256, 0, stream>>>(
        xb, wT, 384, 384, t1, qb_, kb_, vtb, nullptr);

    // attention: QBLK=128 (32 q-rows/wave, LB=3); bid = qb*128 + bh pins XCD
    attn_kernel<<<1024, 256, 0, stream>>>(qb_, kb_, vtb, ab, Obuf);

    // proj GEMM: DUAL-B — K loop over 512, A staged once, W_hi+W_lo both
    // staged per tile (48 MFMA per barrier-pair, A traffic halved)
    gemm_bt<128, 96, 1, 128, 4, 3, 1><<<512, 256, 0, stream>>>(
        Obuf, pwT, 512, 512, t2, nullptr, nullptr, nullptr, (float*)d_out);
}

// Round 23
// 99.583 us; speedup vs baseline: 1.0110x; 1.0110x over previous
//
#include <hip/hip_runtime.h>
#include <hip/hip_bf16.h>
#include <cstdint>

typedef __attribute__((ext_vector_type(8))) short bf16x8;
typedef __attribute__((ext_vector_type(4))) float f32x4;
typedef __attribute__((ext_vector_type(4))) unsigned int u32x4;
typedef __attribute__((ext_vector_type(2))) unsigned int u32x2;
typedef __attribute__((ext_vector_type(8))) unsigned short u16x8;
typedef __attribute__((ext_vector_type(4))) unsigned short u16x4;

#define DEV static __device__ __forceinline__

DEV unsigned short f2b(float x) {
    __hip_bfloat16 b = __float2bfloat16(x);
    return __builtin_bit_cast(unsigned short, b);
}
DEV float b2f(unsigned short u) {
    __hip_bfloat16 b = __builtin_bit_cast(__hip_bfloat16, u);
    return __bfloat162float(b);
}
// 2xf32 -> packed bf16x2 dword via HIP intrinsic (emits v_cvt_pk_bf16_f32;
// RNE, bit-identical to f2b pair). a -> low 16 bits. memcpy because
// __hip_bfloat162 is not trivially copyable (bit_cast rejected).
DEV unsigned pk2(float a, float b) {
    __hip_bfloat162 h = __float22bfloat162_rn(float2{a, b});
    unsigned r;
    __builtin_memcpy(&r, &h, 4);
    return r;
}

// raw v_exp_f32 (exp2); flushes exp2(x<-126) to 0 — right for softmax.
#if __has_builtin(__builtin_amdgcn_exp2f)
#define EXP2(x) __builtin_amdgcn_exp2f(x)
#else
#define EXP2(x) exp2f(x)
#endif

// async global->LDS, 16B per lane. LDS base wave-uniform; HW adds lane*16.
typedef __attribute__((address_space(1))) unsigned char as1_u8;
typedef __attribute__((address_space(3))) unsigned char as3_u8;
DEV void gload16(const void* g, void* l) {
    __builtin_amdgcn_global_load_lds((as1_u8*)(uintptr_t)g, (as3_u8*)(uintptr_t)l,
                                     16, 0, 0);
}

#define LOG2E 1.4426950408889634f

// ---------------------------------------------------------------------------
// merged prep: [0,1536) qkv weights | [1536,2304) proj weights | rest: x->bf16
// ---------------------------------------------------------------------------
__global__ void prep_all(const float* __restrict__ qw, const float* __restrict__ qg,
                         const float* __restrict__ qbe, const float* __restrict__ qmu,
                         const float* __restrict__ qva,
                         const float* __restrict__ pw, const float* __restrict__ pg,
                         const float* __restrict__ pbe, const float* __restrict__ pmu,
                         const float* __restrict__ pva,
                         const float* __restrict__ x,
                         unsigned short* __restrict__ wT, float* __restrict__ t1,
                         unsigned short* __restrict__ pwT, float* __restrict__ t2,
                         unsigned short* __restrict__ xb)
{
    int blk = blockIdx.x, tid = threadIdx.x;
    if (blk < 1536) {                       // qkv W: fold BN, transpose, q*SCALE*log2e
        int gid = blk * 256 + tid;
        int c = gid & 1023, k = gid >> 10;
        float s = qg[c] * rsqrtf(qva[c] + 1e-5f);
        float qs = ((c & 127) < 32) ? (0.17677669529663687f * LOG2E) : 1.0f;
        float val = qw[(size_t)k * 1024 + c] * s * qs;
        wT[(size_t)c * 384 + k] = f2b(val);
        if (k == 0) t1[c] = (qbe[c] - qmu[c] * s) * qs;
    } else if (blk < 2304) {                // proj W: hi/lo split -> [W_hi | W_lo]
        int gid = (blk - 1536) * 256 + tid;
        int c = gid % 384, k = gid / 384;
        float s = pg[c] * rsqrtf(pva[c] + 1e-5f);
        float val = pw[(size_t)k * 384 + c] * s;
        unsigned short hi = f2b(val);
        unsigned short lo = f2b(val - b2f(hi));
        size_t base = (size_t)c * 1024;
        pwT[base + k]       = hi;
        pwT[base + 512 + k] = lo;
        if (k == 0) t2[c] = pbe[c] - pmu[c] * s;
    } else {                                // x fp32 -> bf16, 8 elems/thread
        int gid = (blk - 2304) * 256 + tid;
        const f32x4* p = (const f32x4*)(x + (size_t)gid * 8);
        f32x4 a = p[0], bq = p[1];
        u16x8 o;
        #pragma unroll
        for (int t = 0; t < 4; ++t) { o[t] = f2b(a[t]); o[4 + t] = f2b(bq[t]); }
        *(u16x8*)(xb + (size_t)gid * 8) = o;
    }
}

// ---------------------------------------------------------------------------
// GEMM: C[M,N] = A[M,K] * Bt[N,K]^T (+tvec[col]).  m97 2-barrier loop, both
// tiles via global_load_lds width-16.  1D grid, XCD-swizzled.
// DUAL=1 (proj): B has layout [N][2*Kdim] = [W_hi | W_lo]; per k-tile the A
// tile is staged ONCE and BOTH B halves are staged; inner loop runs hi+lo
// MFMAs into the same acc (2x MFMA per barrier, A traffic halved).
// EPI=0: q/k scatter bf16 + V written directly transposed (vt[bh][vd][tok]).
// EPI=1: fp32 out (proj).  LB: min blocks/CU for launch_bounds.
// ---------------------------------------------------------------------------
template<int BM, int BN, int EPI, int MB, int NB, int LB, int DUAL>
__launch_bounds__(256, LB)
__global__ void gemm_bt(const unsigned short* __restrict__ Ab,
                        const unsigned short* __restrict__ Bt,
                        int Kdim, int Astride,
                        const float* __restrict__ tvec,
                        unsigned short* __restrict__ outq,
                        unsigned short* __restrict__ outk,
                        unsigned short* __restrict__ outvt,
                        float* __restrict__ outf)
{
    constexpr int BK = 64;
    constexpr int WM = BM / 2, WN = BN / 2;
    constexpr int MI = WM / 16, NI = WN / 16;
    constexpr int NCA = BM * 128 / 1024; // 1KB wave-chunks in A tile
    constexpr int NCB = BN * 128 / 1024;
    constexpr int NH = DUAL ? 2 : 1;

    __shared__ __align__(16) unsigned short As[BM * BK];
    __shared__ __align__(16) unsigned short Bs[NH * BN * BK];

    const int tid = threadIdx.x;
    const int lane = tid & 63, w = tid >> 6;
    const int l15 = lane & 15, lg = lane >> 4;
    const int wr = w >> 1, wc = w & 1;

    const int bid = blockIdx.x;
    const int xcd = bid & 7, idx = bid >> 3;
    const int m0 = (xcd * (MB / 8) + idx / NB) * BM;
    const int n0 = (idx % NB) * BN;

    const int brstride = DUAL ? 2 * Kdim : Kdim;   // B row stride (elems)

    f32x4 acc[MI][NI];
    #pragma unroll
    for (int i = 0; i < MI; ++i)
        #pragma unroll
        for (int j = 0; j < NI; ++j) acc[i][j] = (f32x4){0.f, 0.f, 0.f, 0.f};

    const int nk = Kdim / BK;

    for (int kb = 0; kb < nk; ++kb) {
        const int k0 = kb * BK;
        #pragma unroll
        for (int i = 0; i < NCA / 4; ++i) {
            int c = w + i * 4;
            int bo = c * 1024 + lane * 16;
            gload16((const char*)Ab + ((size_t)(m0 + (bo >> 7)) * Astride + k0) * 2 + (bo & 127),
                    (char*)As + c * 1024);
        }
        #pragma unroll
        for (int h2 = 0; h2 < NH; ++h2)
        #pragma unroll
        for (int i = 0; i < NCB / 4; ++i) {
            int c = w + i * 4;
            int bo = c * 1024 + lane * 16;
            gload16((const char*)Bt + ((size_t)(n0 + (bo >> 7)) * brstride + k0 + h2 * Kdim) * 2 + (bo & 127),
                    (char*)Bs + h2 * (BN * BK * 2) + c * 1024);
        }
        __syncthreads();   // drains vmcnt: tile ready

        #pragma unroll
        for (int ks = 0; ks < 2; ++ks) {
            bf16x8 af[MI], bfr[NH][NI];
            #pragma unroll
            for (int mi = 0; mi < MI; ++mi)
                af[mi] = *(const bf16x8*)(&As[(wr * WM + mi * 16 + l15) * 64 + ks * 32 + lg * 8]);
            #pragma unroll
            for (int h2 = 0; h2 < NH; ++h2)
            #pragma unroll
            for (int ni = 0; ni < NI; ++ni)
                bfr[h2][ni] = *(const bf16x8*)(&Bs[h2 * BN * BK +
                                               (wc * WN + ni * 16 + l15) * 64 + ks * 32 + lg * 8]);
            #pragma unroll
            for (int mi = 0; mi < MI; ++mi)
                #pragma unroll
                for (int ni = 0; ni < NI; ++ni) {
                    acc[mi][ni] = __builtin_amdgcn_mfma_f32_16x16x32_bf16(
                        af[mi], bfr[0][ni], acc[mi][ni], 0, 0, 0);
                    if constexpr (DUAL)
                        acc[mi][ni] = __builtin_amdgcn_mfma_f32_16x16x32_bf16(
                            af[mi], bfr[1][ni], acc[mi][ni], 0, 0, 0);
                }
        }
        if (kb + 1 < nk) __syncthreads();
    }

    #pragma unroll
    for (int mi = 0; mi < MI; ++mi)
    #pragma unroll
    for (int ni = 0; ni < NI; ++ni) {
        int col = n0 + wc * WN + ni * 16 + l15;
        int row0 = m0 + wr * WM + mi * 16 + lg * 4;
        if constexpr (EPI == 0) {
            int bb = row0 >> 10, n = row0 & 1023;
            int hh = col >> 7, t = col & 127;
            size_t bhh = (size_t)(bb * 8 + hh);
            if (t < 64) {
                #pragma unroll
                for (int j = 0; j < 4; ++j) {
                    unsigned short bv = f2b(acc[mi][ni][j] + tvec[col]);
                    size_t base = (bhh * 1024 + n + j) * 32;
                    if (t < 32) outq[base + t] = bv;
                    else        outk[base + (t - 32)] = bv;
                }
            } else {
                u16x4 pv;
                #pragma unroll
                for (int j = 0; j < 4; ++j) pv[j] = f2b(acc[mi][ni][j] + tvec[col]);
                *(u16x4*)(outvt + (bhh * 64 + (t - 64)) * 1024 + n) = pv;
            }
        } else {
            #pragma unroll
            for (int j = 0; j < 4; ++j)
                outf[(size_t)(row0 + j) * 384 + col] = acc[mi][ni][j] + tvec[col];
        }
    }
}

// ---------------------------------------------------------------------------
// fused flash attention, SWAPPED QK^T + STATIC-MAX softmax, QBLK=128 (r21
// configuration — best measured): each wave owns 32 q-rows (2 Q-frags
// u=0,1) so the per-64-key-tile V^T LDS reads are amortized over 2x the
// q-rows.  Same-iteration PV; bias read in-loop from LDS biasrow; P stored
// immediately per u; __launch_bounds__(256,3) — no spill (r19's failure).
// Both u-blocks share xi (q-rows 16 apart), so dx is computed once.
// V^T 2-buffered via global_load_lds: stage(kb+1) issues after the
// region-kb barrier into cur^1 while PV(kb) reads cur; counted s_waitcnt
// vmcnt(4) retires the 2 stage ops while this iter's 4 K loads stay in
// flight; vmcnt(0) only on the last iteration.  P = exp2(s) unnormalized
// (logits ~N(0,1.4): accS<=2^24; O=acc/accS scale-invariant).
// 1D grid, bid = qb*128 + bh pins each bh's 8 blocks to one XCD (K/V L2).
// epilogue: /accS, hardswish, single bf16 store -> O[tok][512]
// ---------------------------------------------------------------------------
__launch_bounds__(256, 3)
__global__ void attn_kernel(const unsigned short* __restrict__ q,
                            const unsigned short* __restrict__ kmat,
                            const unsigned short* __restrict__ vt,
                            const float* __restrict__ ab,
                            unsigned short* __restrict__ O)
{
    __shared__ __align__(16) unsigned short Vls[2][64 * 64];  // swizzled [vd][key]
    __shared__ __align__(16) unsigned short Pls[4 * 32 * 64]; // per-wave [q][k]
    __shared__ float biasrow[1024];

    const int tid = threadIdx.x;
    const int lane = tid & 63, w = tid >> 6;
    const int l15 = lane & 15, lg = lane >> 4;
    const int bid = blockIdx.x;
    const int qb = bid >> 7, bh = bid & 127;
    const int h = bh & 7, b = bh >> 3;

    for (int i = tid; i < 1024; i += 256) biasrow[i] = ab[h * 1024 + i] * LOG2E;

    // two Q B-frags per wave (col=q=lane&15, k=d); rows 16 apart share xi
    const int qrow0 = qb * 128 + w * 32 + l15;
    bf16x8 aq[2];
    aq[0] = *(const bf16x8*)(q + ((size_t)bh * 1024 + qrow0) * 32 + lg * 8);
    aq[1] = *(const bf16x8*)(q + ((size_t)bh * 1024 + qrow0 + 16) * 32 + lg * 8);

    const int xi = qrow0 >> 5;            // same for both u (qrow0&31 = l15 < 16)
    int dyoff[2][2][4];                   // |yi(u) - yj(p,j)| * 4 bytes
    #pragma unroll
    for (int u = 0; u < 2; ++u) {
        int yi = l15 + u * 16;
        #pragma unroll
        for (int p = 0; p < 2; ++p)
            #pragma unroll
            for (int j = 0; j < 4; ++j) {
                int d = yi - (p * 16 + lg * 4 + j);
                dyoff[u][p][j] = (d < 0 ? -d : d) * 4;
            }
    }

    f32x4 acc[2][4], accS[2];
    #pragma unroll
    for (int u = 0; u < 2; ++u) {
        #pragma unroll
        for (int cf = 0; cf < 4; ++cf) acc[u][cf] = (f32x4){0.f, 0.f, 0.f, 0.f};
        accS[u] = (f32x4){0.f, 0.f, 0.f, 0.f};
    }

    const short oneb = (short)0x3F80;
    const bf16x8 onesb = {oneb, oneb, oneb, oneb, oneb, oneb, oneb, oneb};

    const unsigned short* kbase = kmat + (size_t)bh * 1024 * 32 + lg * 8;

    // V gload_lds geometry: lane feeds rows vrow / vrow+32 with pre-swizzled
    // source key chunk so the XOR LDS layout materializes.
    const int vrow = w * 8 + (lane >> 3);
    const int vkel = ((lane & 7) ^ (lane >> 3)) * 8;
    const unsigned short* vsrc0 = vt + ((size_t)bh * 64 + vrow) * 1024 + vkel;
    const unsigned short* vsrc1 = vsrc0 + (size_t)32 * 1024;

    // P bases: wave block 4KB; row u*16+l15; swizzle (l15&7)<<4 (row&7=l15&7)
    char* const pw_base = (char*)Pls + w * 4096 + l15 * 128;
    const int pswz = (l15 & 7) << 4;

    // prolog: stage V tile 0 (async), prefetch K frags for tile 0
    gload16(vsrc0, (char*)Vls[0] + w * 1024);
    gload16(vsrc1, (char*)Vls[0] + w * 1024 + 4096);
    bf16x8 kf[4];
    #pragma unroll
    for (int cf = 0; cf < 4; ++cf)
        kf[cf] = *(const bf16x8*)(kbase + (size_t)(cf * 16 + l15) * 32);
    __syncthreads();   // full drain once: covers biasrow + Vls[0]

    int cur = 0;
    for (int kb = 0; kb < 16; ++kb) {
        // bias x-distance (shared by both u; 2 per iter, lane-scalar)
        int dx0 = xi - 2 * kb;     dx0 = (dx0 < 0 ? -dx0 : dx0) * 128;
        int dx1 = xi - 2 * kb - 1; dx1 = (dx1 < 0 ? -dx1 : dx1) * 128;

        // per u: bias C-in (LDS, in-loop), QK(kb), exp/pack, store P(u).
        // s[] is transient per u — keeps live registers minimal.
        #pragma unroll
        for (int u = 0; u < 2; ++u) {
            f32x4 s[4];
            __builtin_amdgcn_s_setprio(1);
            #pragma unroll
            for (int cf = 0; cf < 4; ++cf) {
                const int dxo = (cf >> 1) ? dx1 : dx0;
                f32x4 c;
                #pragma unroll
                for (int j = 0; j < 4; ++j)
                    c[j] = *(const float*)((const char*)biasrow +
                                           (dxo + dyoff[u][cf & 1][j]));
                s[cf] = __builtin_amdgcn_mfma_f32_16x16x32_bf16(
                    kf[cf], aq[u], c, 0, 0, 0);
            }
            __builtin_amdgcn_s_setprio(0);
            char* pwu = pw_base + u * 2048;
            #pragma unroll
            for (int cf = 0; cf < 4; ++cf) {
                unsigned lo = pk2(EXP2(s[cf][0]), EXP2(s[cf][1]));
                unsigned hi = pk2(EXP2(s[cf][2]), EXP2(s[cf][3]));
                *(u32x2*)(pwu + ((cf * 32 + lg * 8) ^ pswz)) = (u32x2){lo, hi};
            }
        }

        // K frags for kb+1 (after both QKs consumed the old ones)
        if (kb < 15) {
            #pragma unroll
            for (int cf = 0; cf < 4; ++cf)
                kf[cf] = *(const bf16x8*)(kbase + (size_t)((kb + 1) * 64 + cf * 16 + l15) * 32);
        }

        // counted-vmcnt barrier: newer ops = 4 K loads; waiting to 4 retires
        // the 2 older V-stage gloads (in-order). Last iter: full drain.
        if (kb < 15) {
            __asm__ volatile("s_waitcnt vmcnt(4)" ::: "memory");
        } else {
            __asm__ volatile("s_waitcnt vmcnt(0)" ::: "memory");
        }
        __builtin_amdgcn_s_barrier();

        // region kb: stage V(kb+1) into cur^1 while PV(kb) reads cur
        if (kb < 15) {
            gload16(vsrc0 + (kb + 1) * 64, (char*)Vls[cur ^ 1] + w * 1024);
            gload16(vsrc1 + (kb + 1) * 64, (char*)Vls[cur ^ 1] + w * 1024 + 4096);
        }

        // PV(kb): each V^T frag read once, used by both u-blocks (20 MFMAs)
        __builtin_amdgcn_s_setprio(1);
        #pragma unroll
        for (int ks = 0; ks < 2; ++ks) {
            const bf16x8 pa0 = *(const bf16x8*)(pw_base + ((ks * 64 + lg * 16) ^ pswz));
            const bf16x8 pa1 = *(const bf16x8*)(pw_base + 2048 + ((ks * 64 + lg * 16) ^ pswz));
            accS[0] = __builtin_amdgcn_mfma_f32_16x16x32_bf16(pa0, onesb, accS[0], 0, 0, 0);
            accS[1] = __builtin_amdgcn_mfma_f32_16x16x32_bf16(pa1, onesb, accS[1], 0, 0, 0);
            #pragma unroll
            for (int cf = 0; cf < 4; ++cf) {
                const bf16x8 vb = *(const bf16x8*)((char*)Vls[cur] + (cf * 16 + l15) * 128 +
                                                   ((ks * 64 + lg * 16) ^ (((cf * 16 + l15) & 7) << 4)));
                acc[0][cf] = __builtin_amdgcn_mfma_f32_16x16x32_bf16(pa0, vb, acc[0][cf], 0, 0, 0);
                acc[1][cf] = __builtin_amdgcn_mfma_f32_16x16x32_bf16(pa1, vb, acc[1][cf], 0, 0, 0);
            }
        }
        __builtin_amdgcn_s_setprio(0);

        cur ^= 1;
    }

    // epilogue: normalize, hardswish, single bf16 store per u-block
    #pragma unroll
    for (int u = 0; u < 2; ++u) {
        float rinv[4];
        #pragma unroll
        for (int j = 0; j < 4; ++j) rinv[j] = 1.f / accS[u][j];
        #pragma unroll
        for (int cf = 0; cf < 4; ++cf)
        #pragma unroll
        for (int j = 0; j < 4; ++j) {
            float ov = acc[u][cf][j] * rinv[j];
            float hs = ov * fminf(fmaxf(ov + 3.f, 0.f), 6.f) * (1.f / 6.f);
            size_t tok = (size_t)b * 1024 + qb * 128 + w * 32 + u * 16 + lg * 4 + j;
            O[tok * 512 + h * 64 + cf * 16 + l15] = f2b(hs);
        }
    }
}

// ---------------------------------------------------------------------------
extern "C" void kernel_launch(void* const* d_in, const int* in_sizes, int n_in,
                              void* d_out, int out_size, void* d_ws, size_t ws_size,
                              hipStream_t stream)
{
    const float* x   = (const float*)d_in[0];
    const float* qw  = (const float*)d_in[1];
    const float* qg  = (const float*)d_in[2];
    const float* qbe = (const float*)d_in[3];
    const float* qmu = (const float*)d_in[4];
    const float* qva = (const float*)d_in[5];
    const float* pw  = (const float*)d_in[6];
    const float* pg  = (const float*)d_in[7];
    const float* pbe = (const float*)d_in[8];
    const float* pmu = (const float*)d_in[9];
    const float* pva = (const float*)d_in[10];
    const float* ab  = (const float*)d_in[11];

    char* ws = (char*)d_ws;
    size_t off = 0;
    auto alloc = [&](size_t bytes) {
        size_t o = off; off = (off + bytes + 255) & ~(size_t)255; return o;
    };

    size_t o_o   = alloc((size_t)16384 * 512 * 2);   // O bf16 (plain)
    size_t o_wT  = alloc((size_t)1024 * 384 * 2);
    size_t o_pwT = alloc((size_t)384 * 1024 * 2);    // [W_hi | W_lo]
    size_t o_t1  = alloc(1024 * 4);
    size_t o_t2  = alloc(384 * 4);
    size_t o_q   = alloc((size_t)16 * 8 * 1024 * 32 * 2);
    size_t o_k   = alloc((size_t)16 * 8 * 1024 * 32 * 2);
    size_t o_vt  = alloc((size_t)16 * 8 * 1024 * 64 * 2);
    size_t o_xb  = alloc((size_t)16384 * 384 * 2);

    unsigned short* Obuf = (unsigned short*)(ws + o_o);
    unsigned short* wT   = (unsigned short*)(ws + o_wT);
    unsigned short* pwT  = (unsigned short*)(ws + o_pwT);
    float* t1 = (float*)(ws + o_t1);
    float* t2 = (float*)(ws + o_t2);
    unsigned short* qb_ = (unsigned short*)(ws + o_q);
    unsigned short* kb_ = (unsigned short*)(ws + o_k);
    unsigned short* vtb = (unsigned short*)(ws + o_vt);
    unsigned short* xb  = (unsigned short*)(ws + o_xb);

    prep_all<<<5376, 256, 0, stream>>>(qw, qg, qbe, qmu, qva,
                                       pw, pg, pbe, pmu, pva,
                                       x, wT, t1, pwT, t2, xb);

    // qkv GEMM: both tiles via global_load_lds; 1024 blocks = exactly 4/CU
    gemm_bt<128, 128, 0, 128, 8, 4, 0><<<1024, 256, 0, stream>>>(
        xb, wT, 384, 384, t1, qb_, kb_, vtb, nullptr);

    // attention: QBLK=128 (32 q-rows/wave, LB=3); bid = qb*128 + bh pins XCD
    attn_kernel<<<1024, 256, 0, stream>>>(qb_, kb_, vtb, ab, Obuf);

    // proj GEMM: DUAL-B — K loop over 512, A staged once, W_hi+W_lo both
    // staged per tile (48 MFMA per barrier-pair, A traffic halved)
    gemm_bt<128, 96, 1, 128, 4, 3, 1><<<512, 256, 0, stream>>>(
        Obuf, pwT, 512, 512, t2, nullptr, nullptr, nullptr, (float*)d_out);
}